// Round 7
// baseline (277.368 us; speedup 1.0000x reference)
//
#include <hip/hip_runtime.h>

// SNN policy, dense-MFMA edition (round 12: M=32, two batch-tiles/block).
// Block = 4 waves = 32 batch elements as TWO independent 16-row tiles
// (A, B) sharing weight registers. Wave w owns neuron slice [32w, 32w+32).
// Weights as EXACT-ish 2-way round-to-nearest bf16 splits (hi + mid, both
// in registers). z spikes: per-tile 16x128 bf16 LDS tiles (swizzled,
// double-buffered), written in C-frag layout, read as A-frags.
//
// r11 post-mortem: all pipes <40% (MFMA 38, VALU ~32, LDS ~22) yet time
// only dropped by the removed conflict cycles -> STALL-BOUND: 3 serial
// dependence chains per SIMD can't cover barrier/ds_read/MFMA-chain
// latency. Fix: more independent streams. M=32 doubles per-wave ILP
// (two interleaved chains), halves barrier count, amortizes weights.
// 2 waves/SIMD x 2 blocks/CU = 4 streams/SIMD with 2x internal ILP.
// Per-element computation graph identical to r11 -> absmax unchanged.
// Registers ~215 < 256 budget at __launch_bounds__(256,2); guard counter
// is WRITE_SIZE == 512 KB (any more = rolling spill = revert).

#pragma clang fp contract(off)

typedef float f32x4 __attribute__((ext_vector_type(4)));
typedef float f32x2 __attribute__((ext_vector_type(2)));
typedef short short8 __attribute__((ext_vector_type(8)));
typedef int int4v __attribute__((ext_vector_type(4)));

constexpr int TSTEPS = 40;

// round-to-nearest-even bf16, returned as f32 bit pattern (low 16 zero)
__device__ __forceinline__ unsigned rnbf(float f) {
    unsigned u = __float_as_uint(f);
    return (u + 0x7FFFu + ((u >> 16) & 1u)) & 0xFFFF0000u;
}

// 2-way RN split of an f32 pair into packed bf16 (lo16 = even-k element)
__device__ __forceinline__ void split2pair(float a, float b,
                                           unsigned& hi, unsigned& mi) {
    unsigned ha = rnbf(a), hb = rnbf(b);
    float ra = a - __uint_as_float(ha);
    float rb = b - __uint_as_float(hb);
    unsigned ma = rnbf(ra), mb = rnbf(rb);
    hi = (ha >> 16) | (hb & 0xFFFF0000u);
    mi = (ma >> 16) | (mb & 0xFFFF0000u);
}

__device__ __forceinline__ f32x4 mfma16(int4v a, int4v b, f32x4 c) {
    return __builtin_amdgcn_mfma_f32_16x16x32_bf16(
        __builtin_bit_cast(short8, a), __builtin_bit_cast(short8, b), c, 0, 0, 0);
}

template <int CTRL>
__device__ __forceinline__ float dpp_mov(float v) {
    return __int_as_float(
        __builtin_amdgcn_update_dpp(0, __float_as_int(v), CTRL, 0xF, 0xF, true));
}

__device__ __forceinline__ f32x2 lo2(f32x4 a) {
    return __builtin_shufflevector(a, a, 0, 1);
}
__device__ __forceinline__ f32x2 hi2(f32x4 a) {
    return __builtin_shufflevector(a, a, 2, 3);
}

__global__ __launch_bounds__(256, 2) void snn_kernel(
    const float* __restrict__ x,
    const float* __restrict__ w_in,
    const float* __restrict__ w_rec,
    const float* __restrict__ w_out,
    float* __restrict__ out)
{
    // [buf:8192][tile:4096][16 rows x 128 cols bf16, swizzled]
    __shared__ char zraw[16384];

    const int tid = threadIdx.x;
    const int l   = tid & 63;
    const int wv  = tid >> 6;      // wave 0..3
    const int cl  = l & 15;        // row (A/write col-lane) / col (B/C)
    const int kg  = l >> 4;        // k-group 0..3
    const int kb  = kg * 8;        // k base within a 32-chunk
    const int b0  = blockIdx.x * 32;
    const int Ns  = wv * 32;       // neuron slice base

    // packed-op constants
    const f32x2 P1  = {0.1f, 0.1f};
    const f32x2 P02 = {0.2f, 0.2f};

    // ---- recurrent weights: BOTH splits -> registers (shared by tiles)
    int4v BrecHi[2][4], BrecMi[2][4];
#pragma unroll
    for (int t = 0; t < 2; ++t) {
        int n = Ns + t * 16 + cl;
#pragma unroll
        for (int kc = 0; kc < 4; ++kc) {
            const float* wp = w_rec + n * 128 + kc * 32 + kb;
            float4 wa = *reinterpret_cast<const float4*>(wp);
            float4 wb = *reinterpret_cast<const float4*>(wp + 4);
            float w8[8] = {wa.x, wa.y, wa.z, wa.w, wb.x, wb.y, wb.z, wb.w};
#pragma unroll
            for (int r = 0; r < 4; ++r) {
                unsigned h, m;
                split2pair(w8[2 * r], w8[2 * r + 1], h, m);
                BrecHi[t][kc][r] = (int)h;
                BrecMi[t][kc][r] = (int)m;
            }
        }
    }

    // ---- input weights, hi+mid PACKED in one B-frag (kg0=hi, kg1=mid)
    int4v BwinPk[2];
#pragma unroll
    for (int t = 0; t < 2; ++t) {
        int n = Ns + t * 16 + cl;
        float w8[8];
#pragma unroll
        for (int j = 0; j < 8; ++j)
            w8[j] = (kg < 2) ? w_in[n * 8 + j] : 0.0f;
#pragma unroll
        for (int r = 0; r < 4; ++r) {
            unsigned h, m;
            split2pair(w8[2 * r], w8[2 * r + 1], h, m);
            BwinPk[t][r] = (int)(kg == 0 ? h : (kg == 1 ? m : 0u));
        }
    }

    // ---- readout weights: cols 0,1 = hi(ch0),hi(ch1); cols 2,3 = mid
    int4v Bwout[4];
    {
        int  ch   = cl & 1;
        int  part = (cl >> 1) & 1;
        bool act  = cl < 4;
#pragma unroll
        for (int kc = 0; kc < 4; ++kc) {
            float w8[8];
#pragma unroll
            for (int j = 0; j < 8; ++j)
                w8[j] = act ? w_out[ch * 128 + kc * 32 + kb + j] : 0.0f;
#pragma unroll
            for (int r = 0; r < 4; ++r) {
                unsigned h, m;
                split2pair(w8[2 * r], w8[2 * r + 1], h, m);
                Bwout[kc][r] = (int)(part ? m : h);
            }
        }
    }

    // ---- encoder: tile A = batches b0..b0+15, tile B = b0+16..b0+31
    float xv0 = x[(size_t)(b0 + (l >> 3)) * 4 + (l & 3)];
    float xv1 = x[(size_t)(b0 + 8 + (l >> 3)) * 4 + (l & 3)];
    float xv2 = x[(size_t)(b0 + 16 + (l >> 3)) * 4 + (l & 3)];
    float xv3 = x[(size_t)(b0 + 24 + (l >> 3)) * 4 + (l & 3)];
    float s0 = 50.0f * xv0, s1 = 50.0f * xv1;
    float s2 = 50.0f * xv2, s3 = 50.0f * xv3;
    f32x2 curA, curB;
    curA[0] = (l & 4) ? fmaxf(-s0, 0.0f) : fmaxf(s0, 0.0f);
    curA[1] = (l & 4) ? fmaxf(-s1, 0.0f) : fmaxf(s1, 0.0f);
    curB[0] = (l & 4) ? fmaxf(-s2, 0.0f) : fmaxf(s2, 0.0f);
    curB[1] = (l & 4) ? fmaxf(-s3, 0.0f) : fmaxf(s3, 0.0f);
    f32x2 veA = {0.0f, 0.0f}, veB = {0.0f, 0.0f};

    // ---- states per tile (C-frag layout)
    f32x2 iSlA[2] = {{0,0},{0,0}}, iShA[2] = {{0,0},{0,0}};
    f32x2 vSlA[2] = {{0,0},{0,0}}, vShA[2] = {{0,0},{0,0}};
    f32x2 iSlB[2] = {{0,0},{0,0}}, iShB[2] = {{0,0},{0,0}};
    f32x2 vSlB[2] = {{0,0},{0,0}}, vShB[2] = {{0,0},{0,0}};
    f32x2 ioA_l = {0,0}, ioA_h = {0,0}, voA_l = {0,0}, voA_h = {0,0};
    f32x2 ioB_l = {0,0}, ioB_h = {0,0}, voB_l = {0,0}, voB_h = {0,0};
    f32x4 mxA = {-3e38f,-3e38f,-3e38f,-3e38f};
    f32x4 mxB = {-3e38f,-3e38f,-3e38f,-3e38f};

    // ---- z-tile LDS addresses (within-tile swizzle identical to r11).
    // tile A = +0, tile B = +4096 (bit12), buffer toggle = bit13 (8192).
    unsigned awrb[2];
#pragma unroll
    for (int t = 0; t < 2; ++t) {
        int col = Ns + t * 16 + cl;
        awrb[t] = (unsigned)((kg * 1024 + col * 2) ^ ((kg & 1) << 6));
    }
    unsigned ard = (unsigned)((cl * 256 + kg * 16) ^ ((cl & 7) << 4)) | 8192u;

    auto loadfrags = [&](int4v* zfA, int4v* zfB) {
#pragma unroll
        for (int kc = 0; kc < 4; ++kc) {
            unsigned a = ard ^ (unsigned)(kc << 6);
            zfA[kc] = *reinterpret_cast<int4v*>(&zraw[a]);
            zfB[kc] = *reinterpret_cast<int4v*>(&zraw[a ^ 4096u]);
        }
    };

    auto readout = [&](const int4v* zfA, const int4v* zfB) {
        f32x4 croA = {0,0,0,0}, croB = {0,0,0,0};
#pragma unroll
        for (int kc = 0; kc < 4; ++kc) {
            croA = mfma16(zfA[kc], Bwout[kc], croA);
            croB = mfma16(zfB[kc], Bwout[kc], croB);
        }
        f32x4 crA, crB;
#pragma unroll
        for (int r = 0; r < 4; ++r) {
            crA[r] = croA[r] + dpp_mov<0x4E>(croA[r]);
            crB[r] = croB[r] + dpp_mov<0x4E>(croB[r]);
        }
        // tile A
        {
            f32x2 t2l = ioA_l - voA_l;
            f32x2 t2h = ioA_h - voA_h;
            f32x2 vnl = voA_l + P1 * t2l;
            f32x2 vnh = voA_h + P1 * t2h;
            ioA_l = (ioA_l - P02 * ioA_l) + lo2(crA);
            ioA_h = (ioA_h - P02 * ioA_h) + hi2(crA);
            voA_l = vnl;
            voA_h = vnh;
            mxA[0] = fmaxf(mxA[0], vnl[0]);
            mxA[1] = fmaxf(mxA[1], vnl[1]);
            mxA[2] = fmaxf(mxA[2], vnh[0]);
            mxA[3] = fmaxf(mxA[3], vnh[1]);
        }
        // tile B
        {
            f32x2 t2l = ioB_l - voB_l;
            f32x2 t2h = ioB_h - voB_h;
            f32x2 vnl = voB_l + P1 * t2l;
            f32x2 vnh = voB_h + P1 * t2h;
            ioB_l = (ioB_l - P02 * ioB_l) + lo2(crB);
            ioB_h = (ioB_h - P02 * ioB_h) + hi2(crB);
            voB_l = vnl;
            voB_h = vnh;
            mxB[0] = fmaxf(mxB[0], vnl[0]);
            mxB[1] = fmaxf(mxB[1], vnl[1]);
            mxB[2] = fmaxf(mxB[2], vnh[0]);
            mxB[3] = fmaxf(mxB[3], vnh[1]);
        }
    };

    auto make_axt = [&](unsigned long long bm0, unsigned long long bm1) {
        unsigned long long src = (cl < 8) ? (bm0 >> (cl * 8)) : (bm1 >> ((cl - 8) * 8));
        unsigned byt = (l < 32) ? ((unsigned)src & 0xFFu) : 0u;
        int4v axt;
        axt[0] = (int)(((byt & 1u)   ? 0x3F80u : 0u) | ((byt & 2u)   ? 0x3F800000u : 0u));
        axt[1] = (int)(((byt & 4u)   ? 0x3F80u : 0u) | ((byt & 8u)   ? 0x3F800000u : 0u));
        axt[2] = (int)(((byt & 16u)  ? 0x3F80u : 0u) | ((byt & 32u)  ? 0x3F800000u : 0u));
        axt[3] = (int)(((byt & 64u)  ? 0x3F80u : 0u) | ((byt & 128u) ? 0x3F800000u : 0u));
        return axt;
    };

    auto encoder_lif = [&](bool with_rec, const int4v* zfA, const int4v* zfB) {
        // encoder, both tiles (bit-exact np chain per tile)
        f32x2 teA = curA - veA;
        f32x2 vvA = veA + P1 * teA;
        f32x2 teB = curB - veB;
        f32x2 vvB = veB + P1 * teB;
        bool e0 = vvA[0] > 1.0f, e1 = vvA[1] > 1.0f;
        bool e2 = vvB[0] > 1.0f, e3 = vvB[1] > 1.0f;
        unsigned long long bm0A = __ballot(e0), bm1A = __ballot(e1);
        unsigned long long bm0B = __ballot(e2), bm1B = __ballot(e3);
        veA[0] = e0 ? 0.0f : vvA[0];
        veA[1] = e1 ? 0.0f : vvA[1];
        veB[0] = e2 ? 0.0f : vvB[0];
        veB[1] = e3 ? 0.0f : vvB[1];
        int4v axtA = make_axt(bm0A, bm1A);
        int4v axtB = make_axt(bm0B, bm1B);
#pragma unroll
        for (int t = 0; t < 2; ++t) {
            f32x4 cinA = {0,0,0,0}, cinB = {0,0,0,0};
            cinA = mfma16(axtA, BwinPk[t], cinA);
            cinB = mfma16(axtB, BwinPk[t], cinB);
            f32x4 crecA = {0,0,0,0}, crecB = {0,0,0,0};
            if (with_rec) {
#pragma unroll
                for (int kc = 0; kc < 4; ++kc) {
                    crecA = mfma16(zfA[kc], BrecMi[t][kc], crecA);
                    crecB = mfma16(zfB[kc], BrecMi[t][kc], crecB);
                }
#pragma unroll
                for (int kc = 0; kc < 4; ++kc) {
                    crecA = mfma16(zfA[kc], BrecHi[t][kc], crecA);
                    crecB = mfma16(zfB[kc], BrecHi[t][kc], crecB);
                }
            }
            // ---- tile A state update + z write
            {
                f32x2 idl = iSlA[t] - P02 * iSlA[t];
                f32x2 idh = iShA[t] - P02 * iShA[t];
                f32x2 ttl = iSlA[t] - vSlA[t];
                f32x2 tth = iShA[t] - vShA[t];
                f32x2 vdl = vSlA[t] + P1 * ttl;
                f32x2 vdh = vShA[t] + P1 * tth;
#pragma unroll
                for (int r = 0; r < 4; ++r) {
                    float vdr = (r < 2) ? vdl[r] : vdh[r - 2];
                    bool zb = vdr > 1.0f;
                    float vres = zb ? 0.0f : vdr;
                    if (r == 0)      vSlA[t][0] = vres;
                    else if (r == 1) vSlA[t][1] = vres;
                    else if (r == 2) vShA[t][0] = vres;
                    else             vShA[t][1] = vres;
                    short zv = zb ? (short)0x3F80 : (short)0;
                    unsigned a = (awrb[t] ^ (unsigned)(r << 4)) + (unsigned)(r * 256);
                    *reinterpret_cast<short*>(&zraw[a]) = zv;
                }
                iSlA[t] = (idl + lo2(cinA)) + lo2(crecA);
                iShA[t] = (idh + hi2(cinA)) + hi2(crecA);
            }
            // ---- tile B state update + z write
            {
                f32x2 idl = iSlB[t] - P02 * iSlB[t];
                f32x2 idh = iShB[t] - P02 * iShB[t];
                f32x2 ttl = iSlB[t] - vSlB[t];
                f32x2 tth = iShB[t] - vShB[t];
                f32x2 vdl = vSlB[t] + P1 * ttl;
                f32x2 vdh = vShB[t] + P1 * tth;
#pragma unroll
                for (int r = 0; r < 4; ++r) {
                    float vdr = (r < 2) ? vdl[r] : vdh[r - 2];
                    bool zb = vdr > 1.0f;
                    float vres = zb ? 0.0f : vdr;
                    if (r == 0)      vSlB[t][0] = vres;
                    else if (r == 1) vSlB[t][1] = vres;
                    else if (r == 2) vShB[t][0] = vres;
                    else             vShB[t][1] = vres;
                    short zv = zb ? (short)0x3F80 : (short)0;
                    unsigned a = ((awrb[t] ^ (unsigned)(r << 4)) + (unsigned)(r * 256)) ^ 4096u;
                    *reinterpret_cast<short*>(&zraw[a]) = zv;
                }
                iSlB[t] = (idl + lo2(cinB)) + lo2(crecB);
                iShB[t] = (idh + hi2(cinB)) + hi2(crecB);
            }
        }
    };

    auto toggle = [&]() {
        ard ^= 8192u;
        awrb[0] ^= 8192u;
        awrb[1] ^= 8192u;
    };

    // ---- u = 0: no recurrent, no readout (z(-1)=0); writes z(0) -> buf0
    encoder_lif(false, nullptr, nullptr);
    __syncthreads();
    toggle();

#pragma unroll 1
    for (int u = 1; u < TSTEPS; ++u) {
        int4v zfA[4], zfB[4];
        loadfrags(zfA, zfB);          // z(u-1), both tiles
        readout(zfA, zfB);            // vo(u-1), io(u-1)
        encoder_lif(true, zfA, zfB);  // i/v/z(u)
        __syncthreads();
        toggle();
    }

    // ---- epilogue: vo(39) from z(39)
    {
        int4v zfA[4], zfB[4];
        loadfrags(zfA, zfB);
        readout(zfA, zfB);
    }

    // ---- softmax over (mx[.][ch0], mx[.][ch1]) and store, both tiles
#pragma unroll
    for (int r = 0; r < 4; ++r) {
        {
            float partner = dpp_mov<0xB1>(mxA[r]);
            float mm = fmaxf(mxA[r], partner);
            float es = expf(mxA[r] - mm);
            float ep = expf(partner - mm);
            float pr = es / (es + ep);
            if (cl < 2) out[(size_t)(b0 + kg * 4 + r) * 2 + cl] = pr;
        }
        {
            float partner = dpp_mov<0xB1>(mxB[r]);
            float mm = fmaxf(mxB[r], partner);
            float es = expf(mxB[r] - mm);
            float ep = expf(partner - mm);
            float pr = es / (es + ep);
            if (cl < 2) out[(size_t)(b0 + 16 + kg * 4 + r) * 2 + cl] = pr;
        }
    }
}

extern "C" void kernel_launch(void* const* d_in, const int* in_sizes, int n_in,
                              void* d_out, int out_size, void* d_ws, size_t ws_size,
                              hipStream_t stream) {
    const float* x     = (const float*)d_in[0];
    const float* w_in  = (const float*)d_in[1];
    const float* w_rec = (const float*)d_in[2];
    const float* w_out = (const float*)d_in[3];
    float* out = (float*)d_out;

    int B = in_sizes[0] / 4;      // x is (B, 4)
    int blocks = B / 32;          // 32 batch elements per 256-thread block
    snn_kernel<<<blocks, 256, 0, stream>>>(x, w_in, w_rec, w_out, out);
}